// Round 2
// baseline (423.693 us; speedup 1.0000x reference)
//
#include <hip/hip_runtime.h>

// TemporalXORReservoirNetwork: 200-step LIF reservoir, batch rows independent.
//
// R2 design: speculative decoupling. Threads only couple through spikes, and
// the dynamics are identical to the uncoupled system up to and including the
// first spike in the batch row. Threshold 1.0 is ~8 sigma above the stationary
// V distribution (Xavier Win, beta=0.9), so spikes never occur (absmax=0 in R1
// confirmed the all-zero output). Fast path: 200 steps, NO barriers, no LDS
// spike traffic — each thread simulates its 4 neurons and streams float4
// spike values to out. One end-of-kernel vote; if any spike happened, re-run
// the fully-coupled barrier-per-step loop from t=0 and overwrite (correctness
// insurance, never taken in practice).
//
// Floor: spk_rec write = 419 MB @ ~6.3 TB/s ≈ 67 us (the harness's ~268 us
// 1.68 GB poison fill in the timed graph is a fixed cost on top).

#define SEQ    200
#define BATCH  256
#define NRES   2048
#define NTHR   512          // 8 waves; 4 neurons/thread -> float4 stores
#define BETA_F 0.9f

__global__ __launch_bounds__(NTHR, 1) void snn_reservoir_kernel(
    const float* __restrict__ x,     // [200, 256, 3]
    const float* __restrict__ W,     // [2048, 2048]  (row k -> col n)
    const float* __restrict__ Win,   // [2048, 3]
    const float* __restrict__ Wout,  // [2, 2048]
    float* __restrict__ out)         // spk_rec [200,256,2048] then logits [256,2]
{
    const int b    = blockIdx.x;
    const int tid  = threadIdx.x;
    const int lane = tid & 63;
    const int wid  = tid >> 6;        // 0..7
    const int n0   = tid << 2;        // neurons n0..n0+3

    __shared__ float4 sx[SEQ];                    // x[:, b, :]
    __shared__ unsigned long long smask[2][32];   // slow path: spike bitmask
    __shared__ int   scum[2];                     // slow path: cumulative spike count
    __shared__ float red[2][8];
    __shared__ int   anyflag;

    for (int t = tid; t < SEQ; t += NTHR) {
        const float* p = x + (size_t)t * (BATCH * 3) + b * 3;
        sx[t] = make_float4(p[0], p[1], p[2], 0.0f);
    }
    if (tid == 0) anyflag = 0;

    // Input weights for 4 neurons, resident in registers for all 200 steps
    float wi[4][3];
    #pragma unroll
    for (int j = 0; j < 4; ++j) {
        const float* p = Win + (size_t)(n0 + j) * 3;
        wi[j][0] = p[0]; wi[j][1] = p[1]; wi[j][2] = p[2];
    }

    float V[4]  = {0.f, 0.f, 0.f, 0.f};
    int   cnt[4] = {0, 0, 0, 0};

    __syncthreads();   // staging + anyflag visible

    // ---------------- FAST PATH: uncoupled, barrier-free ----------------
    {
        float* po = out + (size_t)b * NRES + n0;
        bool spiked = false;
        #pragma unroll 2
        for (int t = 0; t < SEQ; ++t) {
            const float4 xv = sx[t];
            float4 sp;
            #pragma unroll
            for (int j = 0; j < 4; ++j) {
                const float cur = fmaf(xv.x, wi[j][0],
                                  fmaf(xv.y, wi[j][1], xv.z * wi[j][2]));
                V[j] = fmaf(BETA_F, V[j], cur);
                const bool s = (V[j] >= 1.0f);
                spiked |= s;
                V[j] = s ? 0.f : V[j];
                ((float*)&sp)[j] = s ? 1.f : 0.f;
                if (t >= SEQ - 10) cnt[j] += (int)s;
            }
            *(float4*)po = sp;
            po += BATCH * NRES;
        }
        const unsigned long long bal = __ballot(spiked);
        if (lane == 0 && bal != 0ull) atomicOr(&anyflag, 1);
    }
    __syncthreads();

    // ---------------- SLOW PATH: coupled re-run (never taken) ----------------
    if (anyflag) {
        #pragma unroll
        for (int j = 0; j < 4; ++j) { V[j] = 0.f; cnt[j] = 0; }
        if (tid < 64) smask[tid >> 5][tid & 31] = 0ull;
        if (tid < 2)  scum[tid] = 0;
        __syncthreads();

        int seen[2] = {0, 0};
        float* po = out + (size_t)b * NRES + n0;
        for (int t = 0; t < SEQ; ++t) {
            const int curp = t & 1, prev = curp ^ 1;
            float rec[4] = {0.f, 0.f, 0.f, 0.f};
            const int c = scum[prev];
            if (c != seen[prev]) {            // spikes at step t-1: gather W rows
                seen[prev] = c;
                #pragma unroll 1
                for (int u = 0; u < 32; ++u) {
                    unsigned long long m = smask[prev][u];
                    const int kbase = ((u >> 2) << 8) + (u & 3);
                    while (m) {
                        const int l = __builtin_ctzll(m);
                        m &= m - 1;
                        const int k = kbase + (l << 2);
                        const float4 wv = *(const float4*)(W + (size_t)k * NRES + n0);
                        rec[0] += wv.x; rec[1] += wv.y;
                        rec[2] += wv.z; rec[3] += wv.w;
                    }
                }
            }
            const float4 xv = sx[t];
            float4 sp;
            int pc = 0;
            unsigned long long bj[4];
            #pragma unroll
            for (int j = 0; j < 4; ++j) {
                const float cur = fmaf(xv.x, wi[j][0],
                                  fmaf(xv.y, wi[j][1], xv.z * wi[j][2])) + rec[j];
                V[j] = fmaf(BETA_F, V[j], cur);
                const bool s = (V[j] >= 1.0f);
                V[j] = s ? 0.f : V[j];
                ((float*)&sp)[j] = s ? 1.f : 0.f;
                if (t >= SEQ - 10) cnt[j] += (int)s;
                bj[j] = __ballot(s);
                pc += (int)s;
            }
            *(float4*)po = sp;
            po += BATCH * NRES;
            if (lane == 0) {
                #pragma unroll
                for (int j = 0; j < 4; ++j) smask[curp][(wid << 2) + j] = bj[j];
            }
            // popcount across wave is just sum of per-lane pc via the ballots:
            if (lane == 0) {
                int wpc = 0;
                #pragma unroll
                for (int j = 0; j < 4; ++j) wpc += __popcll(bj[j]);
                if (wpc) atomicAdd(&scum[curp], wpc);
            }
            __syncthreads();
        }
    }

    // ---------------- logits epilogue ----------------
    const float4 w0 = *(const float4*)(Wout + n0);
    const float4 w1 = *(const float4*)(Wout + NRES + n0);
    float p0 = cnt[0] * 0.1f * w0.x + cnt[1] * 0.1f * w0.y +
               cnt[2] * 0.1f * w0.z + cnt[3] * 0.1f * w0.w;
    float p1 = cnt[0] * 0.1f * w1.x + cnt[1] * 0.1f * w1.y +
               cnt[2] * 0.1f * w1.z + cnt[3] * 0.1f * w1.w;
    #pragma unroll
    for (int off = 32; off > 0; off >>= 1) {
        p0 += __shfl_down(p0, off);
        p1 += __shfl_down(p1, off);
    }
    if (lane == 0) { red[0][wid] = p0; red[1][wid] = p1; }
    __syncthreads();
    if (tid == 0) {
        float q0 = 0.f, q1 = 0.f;
        #pragma unroll
        for (int i = 0; i < 8; ++i) { q0 += red[0][i]; q1 += red[1][i]; }
        const size_t loff = (size_t)SEQ * BATCH * NRES;
        out[loff + b * 2 + 0] = q0;
        out[loff + b * 2 + 1] = q1;
    }
}

extern "C" void kernel_launch(void* const* d_in, const int* in_sizes, int n_in,
                              void* d_out, int out_size, void* d_ws, size_t ws_size,
                              hipStream_t stream) {
    const float* x    = (const float*)d_in[0];
    const float* W    = (const float*)d_in[1];
    const float* Win  = (const float*)d_in[2];
    const float* Wout = (const float*)d_in[3];
    float* out = (float*)d_out;
    hipLaunchKernelGGL(snn_reservoir_kernel, dim3(BATCH), dim3(NTHR), 0, stream,
                       x, W, Win, Wout, out);
}